// Round 22
// baseline (156.032 us; speedup 1.0000x reference)
//
#include <hip/hip_runtime.h>
#include <math.h>

#define N_NODES 50000
#define N_EDGESI 800000
#define E_TOT   850000      // + self loops
#define HIDDEN  128
#define HEADS   8
#define HEAD_DIM 16
#define INPUT   300
#define KPADW   384         // padded bf16 word row length
#define BATCH   64

// counting-sort CSR build
#define NR    128
#define RSZ   391
#define CAP   8192
#define CHUNK 2048
#define NSB   ((E_TOT + CHUNK - 1)/CHUNK)   // 416
#define FCAP  8192          // 1-hop frontier capacity

typedef __bf16 bf16_t;
typedef bf16_t bf16x8 __attribute__((ext_vector_type(8)));
typedef bf16_t bf16x2 __attribute__((ext_vector_type(2)));
typedef float  f32x4  __attribute__((ext_vector_type(4)));
typedef float  f32x2  __attribute__((ext_vector_type(2)));

// ===== one-shot: word fp32 [N,300] -> bf16 [N,384] (zero-padded) =====
__global__ __launch_bounds__(256)
void convert_word_kernel(const float* __restrict__ word, bf16_t* __restrict__ wordb){
    int idx = blockIdx.x*256 + threadIdx.x;          // one bf16x8 group per thread
    if (idx >= N_NODES*(KPADW/8)) return;
    int row = idx / (KPADW/8), g = idx % (KPADW/8);
    int col0 = g*8;
    bf16x8 o;
    #pragma unroll
    for (int q = 0; q < 8; q++){
        int c = col0 + q;
        float f = (c < INPUT) ? word[(size_t)row*INPUT + c] : 0.f;
        o[q] = (bf16_t)f;
    }
    *(bf16x8*)&wordb[(size_t)row*KPADW + col0] = o;
}

// ===== Wa[k][j] = sum_d W[k][(j&7)*16+d]*a[j][d] =====
__global__ void wa_kernel(const float* __restrict__ W, const float* __restrict__ as,
                          const float* __restrict__ ad, float* __restrict__ Wa){
    int k = threadIdx.x;   // 128
    #pragma unroll
    for (int j = 0; j < 8; j++){
        float s1 = 0.f, s2 = 0.f;
        #pragma unroll
        for (int d = 0; d < 16; d++){
            float wv = W[k*128 + j*16 + d];
            s1 += wv * as[j*16 + d];
            s2 += wv * ad[j*16 + d];
        }
        Wa[k*16 + j]     = s1;
        Wa[k*16 + 8 + j] = s2;
    }
}

// ===== fused-pack for layer 0 =====
template<int K_REAL, int K_PAD, int NCOL>
__global__ void fused_pack_kernel(const float* __restrict__ W1, const float* __restrict__ Wg,
                                  const float* __restrict__ Wa, const float* __restrict__ b1,
                                  bf16_t* __restrict__ bF, float* __restrict__ bcomb){
    int idx = blockIdx.x*256 + threadIdx.x;
    if (idx < NCOL){
        float s = 0.f;
        for (int d = 0; d < 128; d++)
            s += b1[d] * ((idx < 128) ? Wg[d*128 + idx] : Wa[d*16 + (idx - 128)]);
        bcomb[idx] = s;
    }
    if (idx >= K_PAD*NCOL) return;
    int k = idx / NCOL, col = idx % NCOL;
    float v = 0.f;
    if (k < K_REAL){
        const float* w1r = W1 + k*128;
        if (col < 128){
            for (int m = 0; m < 128; m++) v += w1r[m] * Wg[m*128 + col];
        } else {
            int jj = col - 128;
            for (int m = 0; m < 128; m++) v += w1r[m] * Wa[m*16 + jj];
        }
    }
    int o = ((k >> 3)*NCOL + col)*8 + (k & 7);
    bF[o] = (bf16_t)v;
}

// ===== pack B + fused Wa (layer 1) =====
template<int K_REAL, int K_PAD, int NCOL, bool ALPHA>
__global__ void pack_b_kernel(const float* __restrict__ B128, const float* __restrict__ as,
                              const float* __restrict__ ad, bf16_t* __restrict__ bHi){
    int idx = blockIdx.x*256 + threadIdx.x;
    if (idx >= K_PAD*NCOL) return;
    int k = idx / NCOL, col = idx % NCOL;
    float v = 0.f;
    if (k < K_REAL){
        if (!ALPHA || col < 128){
            v = B128[k*128 + col];
        } else {
            int jj = col - 128;
            const float* a = (jj < 8) ? (as + jj*16) : (ad + (jj-8)*16);
            const float* wrow = B128 + k*128 + (jj & 7)*16;
            float s = 0.f;
            #pragma unroll
            for (int d = 0; d < 16; d++) s += wrow[d]*a[d];
            v = s;
        }
    }
    int o = ((k >> 3)*NCOL + col)*8 + (k & 7);
    bHi[o] = (bf16_t)v;
}

// ===== MFMA GEMM v6 (+ optional indirect row list with device-side count) =====
template<int K_REAL, int K_PAD, int NT, int GH, int PD, bool A_BF16, bool BIAS_EPI, bool ALPHA, bool OUT8, bool INDIRECT>
__global__ __launch_bounds__(256)
void mfma_gemm6_kernel(const void* __restrict__ A_, const bf16_t* __restrict__ bHi,
                       const float* __restrict__ bias, void* __restrict__ outP,
                       float* __restrict__ asrc_out, float* __restrict__ adst_out, int M,
                       const int* __restrict__ rlist, const int* __restrict__ cnt_ptr)
{
    constexpr int NCOL   = NT * 16;
    constexpr int KSTEPS = K_PAD / 32;
    constexpr int KSPP   = GH / 4;
    constexpr int NPASS  = KSTEPS / KSPP;
    constexpr int PELEM  = GH * NCOL * 8;
    constexpr int SIT    = PELEM / 2048;
    static_assert(KSPP * NPASS == KSTEPS && SIT * 2048 == PELEM, "");
    __shared__ bf16_t blds[PELEM];

    int mEff = M;
    if (INDIRECT) mEff = cnt_ptr[0];
    if ((int)(blockIdx.x*64) >= mEff) return;

    int tid = threadIdx.x, lane = tid & 63, w = tid >> 6;
    int l15 = lane & 15, lg = lane >> 4;
    int m0 = (blockIdx.x*4 + w) * 16;
    int mrow = m0 + l15; if (mrow >= mEff) mrow = mEff - 1;
    int arow_idx = INDIRECT ? rlist[mrow] : mrow;

    const float*  arowF = (const float*) A_ + (size_t)arow_idx*K_REAL;
    const bf16_t* arowB = (const bf16_t*)A_ + (size_t)arow_idx*K_REAL;

    float4 pva[PD], pvb[PD];
    bf16x8 pab[PD];
    #pragma unroll
    for (int i = 0; i < PD; i++){
        int k0 = i*32 + lg*8;
        if (A_BF16){
            pab[i] = *(const bf16x8*)&arowB[k0];
        } else {
            pva[i] = (k0 + 3 < K_REAL) ? *(const float4*)&arowF[k0]     : (float4){0.f,0.f,0.f,0.f};
            pvb[i] = (k0 + 7 < K_REAL) ? *(const float4*)&arowF[k0 + 4] : (float4){0.f,0.f,0.f,0.f};
        }
    }

    f32x4 acc[NT];
    #pragma unroll
    for (int c = 0; c < NT; c++) acc[c] = (f32x4){0.f,0.f,0.f,0.f};

    #pragma unroll
    for (int p = 0; p < NPASS; p++){
        const bf16_t* gB = bHi + (size_t)p*PELEM;
        if (p) __syncthreads();
        #pragma unroll
        for (int it = 0; it < SIT; it++){
            int idx = (tid + it*256)*8;
            *(bf16x8*)&blds[idx] = *(const bf16x8*)&gB[idx];
        }
        __syncthreads();

        #pragma unroll
        for (int i = 0; i < KSPP; i++){
            const int ks = p*KSPP + i;
            const int sl = ks % PD;
            bf16x8 ah;
            if (A_BF16){
                ah = pab[sl];
            } else {
                float4 va = pva[sl], vb = pvb[sl];
                float f[8] = {va.x, va.y, va.z, va.w, vb.x, vb.y, vb.z, vb.w};
                #pragma unroll
                for (int q = 0; q < 8; q++) ah[q] = (bf16_t)f[q];
            }
            if (ks + PD < KSTEPS){
                int k0 = (ks + PD)*32 + lg*8;
                if (A_BF16){
                    pab[sl] = *(const bf16x8*)&arowB[k0];
                } else {
                    pva[sl] = (k0 + 3 < K_REAL) ? *(const float4*)&arowF[k0]     : (float4){0.f,0.f,0.f,0.f};
                    pvb[sl] = (k0 + 7 < K_REAL) ? *(const float4*)&arowF[k0 + 4] : (float4){0.f,0.f,0.f,0.f};
                }
            }
            int gloc = i*4 + lg;
            const bf16_t* b_base = &blds[(gloc*NCOL + l15)*8];
            #pragma unroll
            for (int c = 0; c < NT; c++){
                bf16x8 bh = *(const bf16x8*)&b_base[c*128];
                acc[c] = __builtin_amdgcn_mfma_f32_16x16x32_bf16(ah, bh, acc[c], 0,0,0);
            }
        }
    }

    #pragma unroll
    for (int c = 0; c < 8; c++){
        int col = c*16 + l15;
        float bv = BIAS_EPI ? bias[col] : 0.f;
        #pragma unroll
        for (int r = 0; r < 4; r++){
            int m = m0 + lg*4 + r;
            if (m < mEff){
                int row = INDIRECT ? rlist[m] : m;
                float v = acc[c][r] + bv;
                if (OUT8){
                    int pk = __builtin_amdgcn_cvt_pk_fp8_f32(v, v, 0, false);
                    ((unsigned char*)outP)[(size_t)row*128 + col] = (unsigned char)(pk & 0xff);
                } else {
                    ((bf16_t*)outP)[(size_t)row*128 + col] = (bf16_t)v;
                }
            }
        }
    }
    if (ALPHA){
        float bv8 = BIAS_EPI ? bias[128 + l15] : 0.f;
        #pragma unroll
        for (int r = 0; r < 4; r++){
            int m = m0 + lg*4 + r;
            if (m < mEff){
                int row = INDIRECT ? rlist[m] : m;
                float v = acc[8][r] + bv8;
                if (l15 < 8) asrc_out[row*8 + l15]       = v;
                else         adst_out[row*8 + (l15 - 8)] = v;
            }
        }
    }
}

// ============== CSR build: LDS counting sort ==============
__global__ void zero_cnt_kernel(int* __restrict__ bucket_cnt){
    bucket_cnt[threadIdx.x] = 0;
}

__global__ __launch_bounds__(256)
void block_sort_kernel(const int* __restrict__ ei, int* __restrict__ bucket_cnt,
                       int2* __restrict__ pairs2){
    __shared__ int2 stageL[CHUNK];
    __shared__ int2 sortedL[CHUNK];
    __shared__ unsigned short binL[CHUNK];
    __shared__ int histL[NR], lstartL[NR], lcurL[NR], gofsL[NR];
    int tid = threadIdx.x, b = blockIdx.x;
    int e0 = b*CHUNK, e1 = e0 + CHUNK; if (e1 > E_TOT) e1 = E_TOT;
    int n = e1 - e0;
    if (tid < NR) histL[tid] = 0;
    __syncthreads();
    for (int i = tid; i < n; i += 256){
        int e = e0 + i;
        int s, d;
        if (e < N_EDGESI){ s = ei[e]; d = ei[N_EDGESI + e]; }
        else { s = e - N_EDGESI; d = s; }
        stageL[i] = make_int2(s, d);
        atomicAdd(&histL[d/RSZ], 1);
    }
    __syncthreads();
    if (tid < NR) lstartL[tid] = histL[tid];
    __syncthreads();
    for (int off = 1; off < NR; off <<= 1){
        int t = 0;
        if (tid < NR && tid >= off) t = lstartL[tid - off];
        __syncthreads();
        if (tid < NR) lstartL[tid] += t;
        __syncthreads();
    }
    if (tid < NR){
        int excl = lstartL[tid] - histL[tid];
        lstartL[tid] = excl;
        lcurL[tid]   = excl;
    }
    __syncthreads();
    for (int i = tid; i < n; i += 256){
        int2 pr = stageL[i];
        int bb = pr.y / RSZ;
        int pos = atomicAdd(&lcurL[bb], 1);
        sortedL[pos] = pr;
        binL[pos] = (unsigned short)bb;
    }
    __syncthreads();
    if (tid < NR) gofsL[tid] = atomicAdd(&bucket_cnt[tid], histL[tid]);
    __syncthreads();
    for (int i = tid; i < n; i += 256){
        int bb = binL[i];
        int dst = bb*CAP + gofsL[bb] + (i - lstartL[bb]);
        pairs2[dst] = sortedL[i];
    }
}

__global__ void rbase_scan_kernel(const int* __restrict__ bucket_cnt, int* __restrict__ rbase){
    __shared__ int s[NR];
    int t = threadIdx.x;
    s[t] = bucket_cnt[t];
    __syncthreads();
    for (int off = 1; off < NR; off <<= 1){
        int u = (t >= off) ? s[t - off] : 0;
        __syncthreads();
        s[t] += u;
        __syncthreads();
    }
    rbase[t + 1] = s[t];
    if (t == 0) rbase[0] = 0;
}

__global__ __launch_bounds__(512)
void csr_finalize_kernel(const int2* __restrict__ pairs2, const int* __restrict__ bucket_cnt,
                         const int* __restrict__ rbase, int* __restrict__ col_src,
                         int* __restrict__ row_ptr){
    __shared__ int2 pairsL[CAP];
    __shared__ int  colL[CAP];
    __shared__ int  degL[512];
    __shared__ int  startL[512];
    __shared__ int  curL[512];
    int tid = threadIdx.x, r = blockIdx.x;
    int cnt = bucket_cnt[r], base = rbase[r];
    degL[tid] = 0;
    __syncthreads();
    for (int i = tid; i < cnt; i += 512){
        int2 pr = pairs2[r*CAP + i];
        pairsL[i] = pr;
        atomicAdd(&degL[pr.y - r*RSZ], 1);
    }
    __syncthreads();
    int v = degL[tid];
    for (int off = 1; off < 512; off <<= 1){
        int u = (tid >= off) ? degL[tid - off] : 0;
        __syncthreads();
        degL[tid] += u;
        __syncthreads();
    }
    int excl = degL[tid] - v;
    startL[tid] = excl;
    curL[tid]   = excl;
    __syncthreads();
    for (int i = tid; i < cnt; i += 512){
        int2 pr = pairsL[i];
        int pos = atomicAdd(&curL[pr.y - r*RSZ], 1);
        colL[pos] = pr.x;
    }
    __syncthreads();
    for (int i = tid; i < cnt; i += 512)
        col_src[base + i] = colL[i];
    if (tid < RSZ){
        int node = r*RSZ + tid;
        if (node < N_NODES) row_ptr[node] = base + startL[tid];
    }
    if (r == NR-1 && tid == 0) row_ptr[N_NODES] = E_TOT;
}

// ===== frontier = targets ∪ sources(targets); fcnt[0]=count =====
__global__ void build_frontier_kernel(const int* __restrict__ tgt, const int* __restrict__ row_ptr,
                                      const int* __restrict__ col_src, int* __restrict__ list,
                                      int* __restrict__ fcnt){
    __shared__ int st[64], en[64], ofs[65];
    int t = threadIdx.x;
    if (t < 64){ int d = tgt[t]; st[t] = row_ptr[d]; en[t] = row_ptr[d + 1]; }
    __syncthreads();
    if (t == 0){
        int acc = 64;
        for (int i = 0; i < 64; i++){
            ofs[i] = acc;
            acc += en[i] - st[i];
        }
        if (acc > FCAP) acc = FCAP;
        ofs[64] = acc;
        fcnt[0] = acc;
    }
    __syncthreads();
    if (t < 64) list[t] = tgt[t];
    for (int i = 0; i < 64; i++){
        int n = en[i] - st[i];
        int o = ofs[i];
        for (int j = t; j < n && o + j < FCAP; j += 256)
            list[o + j] = col_src[st[i] + j];
    }
}

// ===== fused per-dst softmax + aggregate + bias + ELU =====
__global__ __launch_bounds__(256)
void gat_aggregate_kernel(const int* __restrict__ row_ptr, const int* __restrict__ col_src,
                          const unsigned char* __restrict__ H8, const float* __restrict__ a_s,
                          const float* __restrict__ a_d, const float* __restrict__ bias,
                          bf16_t* __restrict__ xout, const int* __restrict__ nlist, int nn,
                          const int* __restrict__ nn_ptr){
    __shared__ float alds[4][8][65];
    int wave = threadIdx.x >> 6;
    int lane = threadIdx.x & 63;
    if (nn_ptr) nn = nn_ptr[0];
    int gid = blockIdx.x*4 + wave;
    if (gid >= nn) return;
    int d = nlist ? nlist[gid] : gid;
    int start = row_ptr[d], end = row_ptr[d + 1];
    int deg = end - start;
    int hme = lane >> 3, seg = lane & 7;

    float ad_[8];
    {
        float4 t0 = *(const float4*)&a_d[d*8];
        float4 t1 = *(const float4*)&a_d[d*8 + 4];
        ad_[0]=t0.x; ad_[1]=t0.y; ad_[2]=t0.z; ad_[3]=t0.w;
        ad_[4]=t1.x; ad_[5]=t1.y; ad_[6]=t1.z; ad_[7]=t1.w;
    }

    float acc0 = 0.f, acc1 = 0.f, dh;
    unsigned hoff = 2u*lane;

    if (deg <= 64){
        bool act = lane < deg;
        int sreg = 0;
        float e[8];
        #pragma unroll
        for (int h = 0; h < 8; h++) e[h] = 0.f;
        if (act){
            sreg = col_src[start + lane];
            float4 s0 = *(const float4*)&a_s[sreg*8];
            float4 s1 = *(const float4*)&a_s[sreg*8 + 4];
            float as_[8] = {s0.x,s0.y,s0.z,s0.w,s1.x,s1.y,s1.z,s1.w};
            #pragma unroll
            for (int h = 0; h < 8; h++){
                float v = as_[h] + ad_[h];
                v = v > 0.f ? v : 0.2f*v;
                e[h] = __expf(fminf(v, 70.f));
            }
        }
        unsigned rbase = (unsigned)sreg * 128u;
        #pragma unroll
        for (int h = 0; h < 8; h++) alds[wave][h][lane] = e[h];

        const float* row = &alds[wave][hme][0];
        float s = 0.f;
        #pragma unroll
        for (int j = 0; j < 8; j++) s += row[seg*8 + j];
        s += __shfl_xor(s, 1); s += __shfl_xor(s, 2); s += __shfl_xor(s, 4);
        dh = 1.0f / s;

        float acc0b = 0.f, acc1b = 0.f;
        int iters = (deg + 7) >> 3;
        for (int it = 0; it < iters; it++){
            int p = it*8;
            unsigned o0 = __shfl(rbase, p+0) + hoff, o1 = __shfl(rbase, p+1) + hoff;
            unsigned o2 = __shfl(rbase, p+2) + hoff, o3 = __shfl(rbase, p+3) + hoff;
            unsigned o4 = __shfl(rbase, p+4) + hoff, o5 = __shfl(rbase, p+5) + hoff;
            unsigned o6 = __shfl(rbase, p+6) + hoff, o7 = __shfl(rbase, p+7) + hoff;
            unsigned short g0 = *(const unsigned short*)&H8[o0];
            unsigned short g1 = *(const unsigned short*)&H8[o1];
            unsigned short g2 = *(const unsigned short*)&H8[o2];
            unsigned short g3 = *(const unsigned short*)&H8[o3];
            unsigned short g4 = *(const unsigned short*)&H8[o4];
            unsigned short g5 = *(const unsigned short*)&H8[o5];
            unsigned short g6 = *(const unsigned short*)&H8[o6];
            unsigned short g7 = *(const unsigned short*)&H8[o7];
            float a0 = row[p+0], a1 = row[p+1], a2 = row[p+2], a3 = row[p+3];
            float a4 = row[p+4], a5 = row[p+5], a6 = row[p+6], a7 = row[p+7];
            f32x2 f0 = __builtin_amdgcn_cvt_pk_f32_fp8((int)g0, false);
            f32x2 f1 = __builtin_amdgcn_cvt_pk_f32_fp8((int)g1, false);
            f32x2 f2 = __builtin_amdgcn_cvt_pk_f32_fp8((int)g2, false);
            f32x2 f3 = __builtin_amdgcn_cvt_pk_f32_fp8((int)g3, false);
            f32x2 f4 = __builtin_amdgcn_cvt_pk_f32_fp8((int)g4, false);
            f32x2 f5 = __builtin_amdgcn_cvt_pk_f32_fp8((int)g5, false);
            f32x2 f6 = __builtin_amdgcn_cvt_pk_f32_fp8((int)g6, false);
            f32x2 f7 = __builtin_amdgcn_cvt_pk_f32_fp8((int)g7, false);
            acc0  += f0.x*a0 + f2.x*a2;
            acc1  += f0.y*a0 + f2.y*a2;
            acc0b += f1.x*a1 + f3.x*a3;
            acc1b += f1.y*a1 + f3.y*a3;
            acc0  += f4.x*a4 + f6.x*a6;
            acc1  += f4.y*a4 + f6.y*a6;
            acc0b += f5.x*a5 + f7.x*a7;
            acc1b += f5.y*a5 + f7.y*a7;
        }
        acc0 += acc0b;
        acc1 += acc1b;
    } else {
        float adh = ad_[hme];
        float s = 0.f;
        for (int p = start + seg; p < end; p += 8){
            int sn = col_src[p];
            float v = a_s[sn*8 + hme] + adh;
            v = v > 0.f ? v : 0.2f*v;
            s += __expf(fminf(v, 70.f));
        }
        s += __shfl_xor(s, 1); s += __shfl_xor(s, 2); s += __shfl_xor(s, 4);
        dh = 1.0f / s;
        for (int p = start; p < end; p++){
            int sn = col_src[p];
            float v = a_s[sn*8 + hme] + adh;
            v = v > 0.f ? v : 0.2f*v;
            float a = __expf(fminf(v, 70.f));
            unsigned short g = *(const unsigned short*)&H8[(size_t)sn*128 + hoff];
            f32x2 f = __builtin_amdgcn_cvt_pk_f32_fp8((int)g, false);
            acc0 += f.x*a;
            acc1 += f.y*a;
        }
    }

    float o0 = acc0*dh + bias[2*lane];
    float o1 = acc1*dh + bias[2*lane + 1];
    o0 = o0 > 0.f ? o0 : expm1f(o0);
    o1 = o1 > 0.f ? o1 : expm1f(o1);
    bf16x2 o = {(bf16_t)o0, (bf16_t)o1};
    *(bf16x2*)&xout[(size_t)d*HIDDEN + 2*lane] = o;
}

// ---- scores + loss fused ----
__global__ void head_kernel(const bf16_t* __restrict__ x, const int* __restrict__ tgt,
                            const float* __restrict__ w, const float* __restrict__ b,
                            float* __restrict__ dout){
    int t = threadIdx.x;   // 64 = BATCH
    const bf16_t* row = x + (size_t)tgt[t]*HIDDEN;
    float v = 0.f;
    #pragma unroll
    for (int c = 0; c < HIDDEN; c += 8){
        bf16x8 xv = *(const bf16x8*)&row[c];
        #pragma unroll
        for (int j = 0; j < 8; j++) v += (float)xv[j] * w[c + j];
    }
    float sc = v + b[0];
    dout[t] = sc;
    float neg = __shfl(sc, t + 32);
    float dlt = 1.0f - (sc - neg);
    float term = (t < 32) ? (dlt > 0.f ? dlt : 0.f) : 0.f;
    #pragma unroll
    for (int m = 32; m >= 1; m >>= 1) term += __shfl_xor(term, m);
    if (t == 0) dout[BATCH] = term * (1.0f/32.0f);
}

extern "C" void kernel_launch(void* const* d_in, const int* in_sizes, int n_in,
                              void* d_out, int out_size, void* d_ws, size_t ws_size,
                              hipStream_t stream) {
    const float* word   = (const float*)d_in[0];
    const int*   ei     = (const int*)  d_in[1];
    const int*   tgt    = (const int*)  d_in[2];
    const float* lin1W  = (const float*)d_in[4];
    const float* lin1b  = (const float*)d_in[5];
    const float* gatW   = (const float*)d_in[6];
    const float* attS   = (const float*)d_in[7];
    const float* attD   = (const float*)d_in[8];
    const float* gatB   = (const float*)d_in[9];
    const float* lin3W  = (const float*)d_in[10];
    const float* lin3b  = (const float*)d_in[11];

    char* ws = (char*)d_ws;
    size_t off = 0;
    bf16_t*        Xb       = (bf16_t*)(ws + off);        off += (size_t)N_NODES*HIDDEN*2;
    unsigned char* H8       = (unsigned char*)(ws + off); off += (size_t)N_NODES*HIDDEN;
    off = (off + 15) & ~(size_t)15;
    bf16_t*  wordb     = (bf16_t*)(ws + off);  off += (size_t)N_NODES*KPADW*2;
    float*   a_s       = (float*)(ws + off);   off += (size_t)N_NODES*HEADS*4;
    float*   a_d       = (float*)(ws + off);   off += (size_t)N_NODES*HEADS*4;
    int*     row_ptr   = (int*)(ws + off);     off += (size_t)(N_NODES + 16)*4;
    int*     col_src   = (int*)(ws + off);     off += (size_t)E_TOT*4;
    int*     bucket_cnt= (int*)(ws + off);     off += 512;
    int*     rbase     = (int*)(ws + off);     off += 1024;
    int*     frontier  = (int*)(ws + off);     off += (size_t)FCAP*4;
    int*     fcnt      = (int*)(ws + off);     off += 64;
    int2*    pairs2    = (int2*)(ws + off);    off += (size_t)NR*CAP*8;
    bf16_t*  bF        = (bf16_t*)(ws + off);  off += (size_t)384*144*2;
    float*   Wa0       = (float*)(ws + off);   off += 128*16*4;
    float*   bcomb     = (float*)(ws + off);   off += 256;
    bf16_t*  b2        = (bf16_t*)(ws + off);  off += (size_t)128*144*2;

    const int GB = ((N_NODES + 15)/16 + 3)/4;   // 782 gemm blocks (full)
    const int FB = FCAP/64;                      // 128 indirect gemm blocks (worst case)
    const int CB = (N_NODES*(KPADW/8) + 255)/256;

    // ---- CSR build (LDS counting sort) + frontier ----
    zero_cnt_kernel    <<<1, NR, 0, stream>>>(bucket_cnt);
    block_sort_kernel  <<<NSB, 256, 0, stream>>>(ei, bucket_cnt, pairs2);
    rbase_scan_kernel  <<<1, NR, 0, stream>>>(bucket_cnt, rbase);
    csr_finalize_kernel<<<NR, 512, 0, stream>>>(pairs2, bucket_cnt, rbase, col_src, row_ptr);
    build_frontier_kernel<<<1, 256, 0, stream>>>(tgt, row_ptr, col_src, frontier, fcnt);

    // ---- word -> bf16 (padded to 384) ----
    convert_word_kernel<<<CB, 256, 0, stream>>>(word, wordb);

    // ---- layer 0, fused GEMM over ALL nodes (bf16 A) ----
    const float* Wg0 = gatW;
    wa_kernel<<<1, 128, 0, stream>>>(Wg0, attS, attD, Wa0);
    fused_pack_kernel<INPUT, 384, 144><<<(384*144 + 255)/256, 256, 0, stream>>>(
        lin1W, Wg0, Wa0, lin1b, bF, bcomb);
    mfma_gemm6_kernel<KPADW, 384, 9, 16, 5, true, true, true, true, false><<<GB, 256, 0, stream>>>(
        wordb, bF, bcomb, H8, a_s, a_d, N_NODES, nullptr, nullptr);
    // layer-0 aggregate: ONLY frontier nodes
    gat_aggregate_kernel<<<FCAP/4, 256, 0, stream>>>(
        row_ptr, col_src, H8, a_s, a_d, gatB, Xb, frontier, 0, fcnt);

    // ---- layer 1: GEMM over frontier rows only; aggregate only targets ----
    {
        const float* W = gatW + (size_t)HIDDEN*HIDDEN;
        pack_b_kernel<HIDDEN, 128, 144, true><<<(128*144 + 255)/256, 256, 0, stream>>>(
            W, attS + HEADS*HEAD_DIM, attD + HEADS*HEAD_DIM, b2);
        mfma_gemm6_kernel<HIDDEN, 128, 9, 16, 4, true, false, true, true, true><<<FB, 256, 0, stream>>>(
            Xb, b2, nullptr, H8, a_s, a_d, N_NODES, frontier, fcnt);
        gat_aggregate_kernel<<<(BATCH + 3)/4, 256, 0, stream>>>(
            row_ptr, col_src, H8, a_s, a_d, gatB + HIDDEN, Xb, tgt, BATCH, nullptr);
    }

    head_kernel<<<1, 64, 0, stream>>>(Xb, tgt, lin3W, lin3b, (float*)d_out);
}

// Round 23
// 123.211 us; speedup vs baseline: 1.2664x; 1.2664x over previous
//
#include <hip/hip_runtime.h>
#include <math.h>

#define N_NODES 50000
#define N_EDGESI 800000
#define E_TOT   850000      // + self loops
#define HIDDEN  128
#define HEADS   8
#define HEAD_DIM 16
#define INPUT   300
#define BATCH   64

// counting-sort CSR build
#define NR    128           // dst ranges
#define RSZ   391           // nodes per range
#define CAP   8192          // max edges per range
#define CHUNK 2048          // edges per sort block
#define NSB   ((E_TOT + CHUNK - 1)/CHUNK)   // 416
#define FCAP  8192          // frontier capacity (targets + their sources)

typedef __bf16 bf16_t;
typedef bf16_t bf16x8 __attribute__((ext_vector_type(8)));
typedef bf16_t bf16x2 __attribute__((ext_vector_type(2)));
typedef float  f32x4  __attribute__((ext_vector_type(4)));
typedef float  f32x2  __attribute__((ext_vector_type(2)));

// ===== Wa[k][j] = sum_d W[k][(j&7)*16+d]*a[j][d] =====
__global__ void wa_kernel(const float* __restrict__ W, const float* __restrict__ as,
                          const float* __restrict__ ad, float* __restrict__ Wa){
    int k = threadIdx.x;   // 128
    #pragma unroll
    for (int j = 0; j < 8; j++){
        float s1 = 0.f, s2 = 0.f;
        #pragma unroll
        for (int d = 0; d < 16; d++){
            float wv = W[k*128 + j*16 + d];
            s1 += wv * as[j*16 + d];
            s2 += wv * ad[j*16 + d];
        }
        Wa[k*16 + j]     = s1;
        Wa[k*16 + 8 + j] = s2;
    }
}

// ===== fused-pack for layer 0 =====
template<int K_REAL, int K_PAD, int NCOL>
__global__ void fused_pack_kernel(const float* __restrict__ W1, const float* __restrict__ Wg,
                                  const float* __restrict__ Wa, const float* __restrict__ b1,
                                  bf16_t* __restrict__ bF, float* __restrict__ bcomb){
    int idx = blockIdx.x*256 + threadIdx.x;
    if (idx < NCOL){
        float s = 0.f;
        for (int d = 0; d < 128; d++)
            s += b1[d] * ((idx < 128) ? Wg[d*128 + idx] : Wa[d*16 + (idx - 128)]);
        bcomb[idx] = s;
    }
    if (idx >= K_PAD*NCOL) return;
    int k = idx / NCOL, col = idx % NCOL;
    float v = 0.f;
    if (k < K_REAL){
        const float* w1r = W1 + k*128;
        if (col < 128){
            for (int m = 0; m < 128; m++) v += w1r[m] * Wg[m*128 + col];
        } else {
            int jj = col - 128;
            for (int m = 0; m < 128; m++) v += w1r[m] * Wa[m*16 + jj];
        }
    }
    int o = ((k >> 3)*NCOL + col)*8 + (k & 7);
    bF[o] = (bf16_t)v;
}

// ===== pack B + fused Wa (layer 1) =====
template<int K_REAL, int K_PAD, int NCOL, bool ALPHA>
__global__ void pack_b_kernel(const float* __restrict__ B128, const float* __restrict__ as,
                              const float* __restrict__ ad, bf16_t* __restrict__ bHi){
    int idx = blockIdx.x*256 + threadIdx.x;
    if (idx >= K_PAD*NCOL) return;
    int k = idx / NCOL, col = idx % NCOL;
    float v = 0.f;
    if (k < K_REAL){
        if (!ALPHA || col < 128){
            v = B128[k*128 + col];
        } else {
            int jj = col - 128;
            const float* a = (jj < 8) ? (as + jj*16) : (ad + (jj-8)*16);
            const float* wrow = B128 + k*128 + (jj & 7)*16;
            float s = 0.f;
            #pragma unroll
            for (int d = 0; d < 16; d++) s += wrow[d]*a[d];
            v = s;
        }
    }
    int o = ((k >> 3)*NCOL + col)*8 + (k & 7);
    bHi[o] = (bf16_t)v;
}

// ===== MFMA GEMM v6 (+ optional indirect row list with device-side count) =====
template<int K_REAL, int K_PAD, int NT, int GH, int PD, bool A_BF16, bool BIAS_EPI, bool ALPHA, bool OUT8, bool INDIRECT>
__global__ __launch_bounds__(256)
void mfma_gemm6_kernel(const void* __restrict__ A_, const bf16_t* __restrict__ bHi,
                       const float* __restrict__ bias, void* __restrict__ outP,
                       float* __restrict__ asrc_out, float* __restrict__ adst_out, int M,
                       const int* __restrict__ rlist, const int* __restrict__ cnt_ptr)
{
    constexpr int NCOL   = NT * 16;
    constexpr int KSTEPS = K_PAD / 32;
    constexpr int KSPP   = GH / 4;
    constexpr int NPASS  = KSTEPS / KSPP;
    constexpr int PELEM  = GH * NCOL * 8;
    constexpr int SIT    = PELEM / 2048;
    static_assert(KSPP * NPASS == KSTEPS && SIT * 2048 == PELEM, "");
    __shared__ bf16_t blds[PELEM];

    int mEff = M;
    if (INDIRECT) mEff = cnt_ptr[0];
    if ((int)(blockIdx.x*64) >= mEff) return;    // uniform block exit

    int tid = threadIdx.x, lane = tid & 63, w = tid >> 6;
    int l15 = lane & 15, lg = lane >> 4;
    int m0 = (blockIdx.x*4 + w) * 16;
    int mrow = m0 + l15; if (mrow >= mEff) mrow = mEff - 1;
    int arow_idx = INDIRECT ? rlist[mrow] : mrow;

    const float*  arowF = (const float*) A_ + (size_t)arow_idx*K_REAL;
    const bf16_t* arowB = (const bf16_t*)A_ + (size_t)arow_idx*K_REAL;

    float4 pva[PD], pvb[PD];
    bf16x8 pab[PD];
    #pragma unroll
    for (int i = 0; i < PD; i++){
        int k0 = i*32 + lg*8;
        if (A_BF16){
            pab[i] = *(const bf16x8*)&arowB[k0];
        } else {
            pva[i] = (k0 + 3 < K_REAL) ? *(const float4*)&arowF[k0]     : (float4){0.f,0.f,0.f,0.f};
            pvb[i] = (k0 + 7 < K_REAL) ? *(const float4*)&arowF[k0 + 4] : (float4){0.f,0.f,0.f,0.f};
        }
    }

    f32x4 acc[NT];
    #pragma unroll
    for (int c = 0; c < NT; c++) acc[c] = (f32x4){0.f,0.f,0.f,0.f};

    #pragma unroll
    for (int p = 0; p < NPASS; p++){
        const bf16_t* gB = bHi + (size_t)p*PELEM;
        if (p) __syncthreads();
        #pragma unroll
        for (int it = 0; it < SIT; it++){
            int idx = (tid + it*256)*8;
            *(bf16x8*)&blds[idx] = *(const bf16x8*)&gB[idx];
        }
        __syncthreads();

        #pragma unroll
        for (int i = 0; i < KSPP; i++){
            const int ks = p*KSPP + i;
            const int sl = ks % PD;
            bf16x8 ah;
            if (A_BF16){
                ah = pab[sl];
            } else {
                float4 va = pva[sl], vb = pvb[sl];
                float f[8] = {va.x, va.y, va.z, va.w, vb.x, vb.y, vb.z, vb.w};
                #pragma unroll
                for (int q = 0; q < 8; q++) ah[q] = (bf16_t)f[q];
            }
            if (ks + PD < KSTEPS){
                int k0 = (ks + PD)*32 + lg*8;
                if (A_BF16){
                    pab[sl] = *(const bf16x8*)&arowB[k0];
                } else {
                    pva[sl] = (k0 + 3 < K_REAL) ? *(const float4*)&arowF[k0]     : (float4){0.f,0.f,0.f,0.f};
                    pvb[sl] = (k0 + 7 < K_REAL) ? *(const float4*)&arowF[k0 + 4] : (float4){0.f,0.f,0.f,0.f};
                }
            }
            int gloc = i*4 + lg;
            const bf16_t* b_base = &blds[(gloc*NCOL + l15)*8];
            #pragma unroll
            for (int c = 0; c < NT; c++){
                bf16x8 bh = *(const bf16x8*)&b_base[c*128];
                acc[c] = __builtin_amdgcn_mfma_f32_16x16x32_bf16(ah, bh, acc[c], 0,0,0);
            }
        }
    }

    #pragma unroll
    for (int c = 0; c < 8; c++){
        int col = c*16 + l15;
        float bv = BIAS_EPI ? bias[col] : 0.f;
        #pragma unroll
        for (int r = 0; r < 4; r++){
            int m = m0 + lg*4 + r;
            if (m < mEff){
                int row = INDIRECT ? rlist[m] : m;
                float v = acc[c][r] + bv;
                if (OUT8){
                    int pk = __builtin_amdgcn_cvt_pk_fp8_f32(v, v, 0, false);
                    ((unsigned char*)outP)[(size_t)row*128 + col] = (unsigned char)(pk & 0xff);
                } else {
                    ((bf16_t*)outP)[(size_t)row*128 + col] = (bf16_t)v;
                }
            }
        }
    }
    if (ALPHA){
        float bv8 = BIAS_EPI ? bias[128 + l15] : 0.f;
        #pragma unroll
        for (int r = 0; r < 4; r++){
            int m = m0 + lg*4 + r;
            if (m < mEff){
                int row = INDIRECT ? rlist[m] : m;
                float v = acc[8][r] + bv8;
                if (l15 < 8) asrc_out[row*8 + l15]       = v;
                else         adst_out[row*8 + (l15 - 8)] = v;
            }
        }
    }
}

// ============== CSR build: LDS counting sort ==============
__global__ void zero_cnt_kernel(int* __restrict__ bucket_cnt){
    bucket_cnt[threadIdx.x] = 0;
}

__global__ __launch_bounds__(256)
void block_sort_kernel(const int* __restrict__ ei, int* __restrict__ bucket_cnt,
                       int2* __restrict__ pairs2){
    __shared__ int2 stageL[CHUNK];
    __shared__ int2 sortedL[CHUNK];
    __shared__ unsigned short binL[CHUNK];
    __shared__ int histL[NR], lstartL[NR], lcurL[NR], gofsL[NR];
    int tid = threadIdx.x, b = blockIdx.x;
    int e0 = b*CHUNK, e1 = e0 + CHUNK; if (e1 > E_TOT) e1 = E_TOT;
    int n = e1 - e0;
    if (tid < NR) histL[tid] = 0;
    __syncthreads();
    for (int i = tid; i < n; i += 256){
        int e = e0 + i;
        int s, d;
        if (e < N_EDGESI){ s = ei[e]; d = ei[N_EDGESI + e]; }
        else { s = e - N_EDGESI; d = s; }
        stageL[i] = make_int2(s, d);
        atomicAdd(&histL[d/RSZ], 1);
    }
    __syncthreads();
    if (tid < NR) lstartL[tid] = histL[tid];
    __syncthreads();
    for (int off = 1; off < NR; off <<= 1){
        int t = 0;
        if (tid < NR && tid >= off) t = lstartL[tid - off];
        __syncthreads();
        if (tid < NR) lstartL[tid] += t;
        __syncthreads();
    }
    if (tid < NR){
        int excl = lstartL[tid] - histL[tid];
        lstartL[tid] = excl;
        lcurL[tid]   = excl;
    }
    __syncthreads();
    for (int i = tid; i < n; i += 256){
        int2 pr = stageL[i];
        int bb = pr.y / RSZ;
        int pos = atomicAdd(&lcurL[bb], 1);
        sortedL[pos] = pr;
        binL[pos] = (unsigned short)bb;
    }
    __syncthreads();
    if (tid < NR) gofsL[tid] = atomicAdd(&bucket_cnt[tid], histL[tid]);
    __syncthreads();
    for (int i = tid; i < n; i += 256){
        int bb = binL[i];
        int dst = bb*CAP + gofsL[bb] + (i - lstartL[bb]);
        pairs2[dst] = sortedL[i];
    }
}

__global__ void rbase_scan_kernel(const int* __restrict__ bucket_cnt, int* __restrict__ rbase){
    __shared__ int s[NR];
    int t = threadIdx.x;
    s[t] = bucket_cnt[t];
    __syncthreads();
    for (int off = 1; off < NR; off <<= 1){
        int u = (t >= off) ? s[t - off] : 0;
        __syncthreads();
        s[t] += u;
        __syncthreads();
    }
    rbase[t + 1] = s[t];
    if (t == 0) rbase[0] = 0;
}

__global__ __launch_bounds__(512)
void csr_finalize_kernel(const int2* __restrict__ pairs2, const int* __restrict__ bucket_cnt,
                         const int* __restrict__ rbase, int* __restrict__ col_src,
                         int* __restrict__ row_ptr){
    __shared__ int2 pairsL[CAP];
    __shared__ int  colL[CAP];
    __shared__ int  degL[512];
    __shared__ int  startL[512];
    __shared__ int  curL[512];
    int tid = threadIdx.x, r = blockIdx.x;
    int cnt = bucket_cnt[r], base = rbase[r];
    degL[tid] = 0;
    __syncthreads();
    for (int i = tid; i < cnt; i += 512){
        int2 pr = pairs2[r*CAP + i];
        pairsL[i] = pr;
        atomicAdd(&degL[pr.y - r*RSZ], 1);
    }
    __syncthreads();
    int v = degL[tid];
    for (int off = 1; off < 512; off <<= 1){
        int u = (tid >= off) ? degL[tid - off] : 0;
        __syncthreads();
        degL[tid] += u;
        __syncthreads();
    }
    int excl = degL[tid] - v;
    startL[tid] = excl;
    curL[tid]   = excl;
    __syncthreads();
    for (int i = tid; i < cnt; i += 512){
        int2 pr = pairsL[i];
        int pos = atomicAdd(&curL[pr.y - r*RSZ], 1);
        colL[pos] = pr.x;
    }
    __syncthreads();
    for (int i = tid; i < cnt; i += 512)
        col_src[base + i] = colL[i];
    if (tid < RSZ){
        int node = r*RSZ + tid;
        if (node < N_NODES) row_ptr[node] = base + startL[tid];
    }
    if (r == NR-1 && tid == 0) row_ptr[N_NODES] = E_TOT;
}

// ===== frontier = targets ∪ sources(targets); count -> fcnt[0] =====
__global__ void build_frontier_kernel(const int* __restrict__ tgt, const int* __restrict__ row_ptr,
                                      const int* __restrict__ col_src, int* __restrict__ list,
                                      int* __restrict__ fcnt){
    __shared__ int st[64], en[64], ofs[65];
    int t = threadIdx.x;
    if (t < 64){ int d = tgt[t]; st[t] = row_ptr[d]; en[t] = row_ptr[d + 1]; }
    __syncthreads();
    if (t == 0){
        int acc = 64;                       // first 64 slots = targets
        for (int i = 0; i < 64; i++){
            ofs[i] = acc;
            int n = en[i] - st[i];
            acc += n;
        }
        if (acc > FCAP) acc = FCAP;         // safety (cannot trigger: deg<<FCAP)
        ofs[64] = acc;
        fcnt[0] = acc;
    }
    __syncthreads();
    if (t < 64) list[t] = tgt[t];
    for (int i = 0; i < 64; i++){
        int n = en[i] - st[i];
        int o = ofs[i];
        for (int j = t; j < n && o + j < FCAP; j += 256)
            list[o + j] = col_src[st[i] + j];
    }
}

// ===== fused per-dst softmax + aggregate + bias + ELU =====
// nlist: optional node list; nn_ptr: optional device count (overrides nn).
__global__ __launch_bounds__(256)
void gat_aggregate_kernel(const int* __restrict__ row_ptr, const int* __restrict__ col_src,
                          const unsigned char* __restrict__ H8, const float* __restrict__ a_s,
                          const float* __restrict__ a_d, const float* __restrict__ bias,
                          bf16_t* __restrict__ xout, const int* __restrict__ nlist, int nn,
                          const int* __restrict__ nn_ptr){
    __shared__ float alds[4][8][65];
    int wave = threadIdx.x >> 6;
    int lane = threadIdx.x & 63;
    if (nn_ptr) nn = nn_ptr[0];
    int gid = blockIdx.x*4 + wave;
    if (gid >= nn) return;
    int d = nlist ? nlist[gid] : gid;
    int start = row_ptr[d], end = row_ptr[d + 1];
    int deg = end - start;
    int hme = lane >> 3, seg = lane & 7;

    float ad_[8];
    {
        float4 t0 = *(const float4*)&a_d[d*8];
        float4 t1 = *(const float4*)&a_d[d*8 + 4];
        ad_[0]=t0.x; ad_[1]=t0.y; ad_[2]=t0.z; ad_[3]=t0.w;
        ad_[4]=t1.x; ad_[5]=t1.y; ad_[6]=t1.z; ad_[7]=t1.w;
    }

    float acc0 = 0.f, acc1 = 0.f, dh;
    unsigned hoff = 2u*lane;

    if (deg <= 64){
        bool act = lane < deg;
        int sreg = 0;
        float e[8];
        #pragma unroll
        for (int h = 0; h < 8; h++) e[h] = 0.f;
        if (act){
            sreg = col_src[start + lane];
            float4 s0 = *(const float4*)&a_s[sreg*8];
            float4 s1 = *(const float4*)&a_s[sreg*8 + 4];
            float as_[8] = {s0.x,s0.y,s0.z,s0.w,s1.x,s1.y,s1.z,s1.w};
            #pragma unroll
            for (int h = 0; h < 8; h++){
                float v = as_[h] + ad_[h];
                v = v > 0.f ? v : 0.2f*v;
                e[h] = __expf(fminf(v, 70.f));
            }
        }
        unsigned rbase = (unsigned)sreg * 128u;
        #pragma unroll
        for (int h = 0; h < 8; h++) alds[wave][h][lane] = e[h];

        const float* row = &alds[wave][hme][0];
        float s = 0.f;
        #pragma unroll
        for (int j = 0; j < 8; j++) s += row[seg*8 + j];
        s += __shfl_xor(s, 1); s += __shfl_xor(s, 2); s += __shfl_xor(s, 4);
        dh = 1.0f / s;

        float acc0b = 0.f, acc1b = 0.f;
        int iters = (deg + 7) >> 3;
        for (int it = 0; it < iters; it++){
            int p = it*8;
            unsigned o0 = __shfl(rbase, p+0) + hoff, o1 = __shfl(rbase, p+1) + hoff;
            unsigned o2 = __shfl(rbase, p+2) + hoff, o3 = __shfl(rbase, p+3) + hoff;
            unsigned o4 = __shfl(rbase, p+4) + hoff, o5 = __shfl(rbase, p+5) + hoff;
            unsigned o6 = __shfl(rbase, p+6) + hoff, o7 = __shfl(rbase, p+7) + hoff;
            unsigned short g0 = *(const unsigned short*)&H8[o0];
            unsigned short g1 = *(const unsigned short*)&H8[o1];
            unsigned short g2 = *(const unsigned short*)&H8[o2];
            unsigned short g3 = *(const unsigned short*)&H8[o3];
            unsigned short g4 = *(const unsigned short*)&H8[o4];
            unsigned short g5 = *(const unsigned short*)&H8[o5];
            unsigned short g6 = *(const unsigned short*)&H8[o6];
            unsigned short g7 = *(const unsigned short*)&H8[o7];
            float a0 = row[p+0], a1 = row[p+1], a2 = row[p+2], a3 = row[p+3];
            float a4 = row[p+4], a5 = row[p+5], a6 = row[p+6], a7 = row[p+7];
            f32x2 f0 = __builtin_amdgcn_cvt_pk_f32_fp8((int)g0, false);
            f32x2 f1 = __builtin_amdgcn_cvt_pk_f32_fp8((int)g1, false);
            f32x2 f2 = __builtin_amdgcn_cvt_pk_f32_fp8((int)g2, false);
            f32x2 f3 = __builtin_amdgcn_cvt_pk_f32_fp8((int)g3, false);
            f32x2 f4 = __builtin_amdgcn_cvt_pk_f32_fp8((int)g4, false);
            f32x2 f5 = __builtin_amdgcn_cvt_pk_f32_fp8((int)g5, false);
            f32x2 f6 = __builtin_amdgcn_cvt_pk_f32_fp8((int)g6, false);
            f32x2 f7 = __builtin_amdgcn_cvt_pk_f32_fp8((int)g7, false);
            acc0  += f0.x*a0 + f2.x*a2;
            acc1  += f0.y*a0 + f2.y*a2;
            acc0b += f1.x*a1 + f3.x*a3;
            acc1b += f1.y*a1 + f3.y*a3;
            acc0  += f4.x*a4 + f6.x*a6;
            acc1  += f4.y*a4 + f6.y*a6;
            acc0b += f5.x*a5 + f7.x*a7;
            acc1b += f5.y*a5 + f7.y*a7;
        }
        acc0 += acc0b;
        acc1 += acc1b;
    } else {
        float adh = ad_[hme];
        float s = 0.f;
        for (int p = start + seg; p < end; p += 8){
            int sn = col_src[p];
            float v = a_s[sn*8 + hme] + adh;
            v = v > 0.f ? v : 0.2f*v;
            s += __expf(fminf(v, 70.f));
        }
        s += __shfl_xor(s, 1); s += __shfl_xor(s, 2); s += __shfl_xor(s, 4);
        dh = 1.0f / s;
        for (int p = start; p < end; p++){
            int sn = col_src[p];
            float v = a_s[sn*8 + hme] + adh;
            v = v > 0.f ? v : 0.2f*v;
            float a = __expf(fminf(v, 70.f));
            unsigned short g = *(const unsigned short*)&H8[(size_t)sn*128 + hoff];
            f32x2 f = __builtin_amdgcn_cvt_pk_f32_fp8((int)g, false);
            acc0 += f.x*a;
            acc1 += f.y*a;
        }
    }

    float o0 = acc0*dh + bias[2*lane];
    float o1 = acc1*dh + bias[2*lane + 1];
    o0 = o0 > 0.f ? o0 : expm1f(o0);
    o1 = o1 > 0.f ? o1 : expm1f(o1);
    bf16x2 o = {(bf16_t)o0, (bf16_t)o1};
    *(bf16x2*)&xout[(size_t)d*HIDDEN + 2*lane] = o;
}

// ---- scores + loss fused ----
__global__ void head_kernel(const bf16_t* __restrict__ x, const int* __restrict__ tgt,
                            const float* __restrict__ w, const float* __restrict__ b,
                            float* __restrict__ dout){
    int t = threadIdx.x;   // 64 = BATCH
    const bf16_t* row = x + (size_t)tgt[t]*HIDDEN;
    float v = 0.f;
    #pragma unroll
    for (int c = 0; c < HIDDEN; c += 8){
        bf16x8 xv = *(const bf16x8*)&row[c];
        #pragma unroll
        for (int j = 0; j < 8; j++) v += (float)xv[j] * w[c + j];
    }
    float sc = v + b[0];
    dout[t] = sc;
    float neg = __shfl(sc, t + 32);
    float dlt = 1.0f - (sc - neg);
    float term = (t < 32) ? (dlt > 0.f ? dlt : 0.f) : 0.f;
    #pragma unroll
    for (int m = 32; m >= 1; m >>= 1) term += __shfl_xor(term, m);
    if (t == 0) dout[BATCH] = term * (1.0f/32.0f);
}

extern "C" void kernel_launch(void* const* d_in, const int* in_sizes, int n_in,
                              void* d_out, int out_size, void* d_ws, size_t ws_size,
                              hipStream_t stream) {
    const float* word   = (const float*)d_in[0];
    const int*   ei     = (const int*)  d_in[1];
    const int*   tgt    = (const int*)  d_in[2];
    const float* lin1W  = (const float*)d_in[4];
    const float* lin1b  = (const float*)d_in[5];
    const float* gatW   = (const float*)d_in[6];
    const float* attS   = (const float*)d_in[7];
    const float* attD   = (const float*)d_in[8];
    const float* gatB   = (const float*)d_in[9];
    const float* lin3W  = (const float*)d_in[10];
    const float* lin3b  = (const float*)d_in[11];

    char* ws = (char*)d_ws;
    size_t off = 0;
    bf16_t*        Xb       = (bf16_t*)(ws + off);        off += (size_t)N_NODES*HIDDEN*2;
    unsigned char* H8       = (unsigned char*)(ws + off); off += (size_t)N_NODES*HIDDEN;
    off = (off + 15) & ~(size_t)15;
    float*   a_s       = (float*)(ws + off);   off += (size_t)N_NODES*HEADS*4;
    float*   a_d       = (float*)(ws + off);   off += (size_t)N_NODES*HEADS*4;
    int*     row_ptr   = (int*)(ws + off);     off += (size_t)(N_NODES + 16)*4;
    int*     col_src   = (int*)(ws + off);     off += (size_t)E_TOT*4;
    int*     bucket_cnt= (int*)(ws + off);     off += 512;
    int*     rbase     = (int*)(ws + off);     off += 1024;
    int*     frontier  = (int*)(ws + off);     off += (size_t)FCAP*4;
    int*     fcnt      = (int*)(ws + off);     off += 64;
    int2*    pairs2    = (int2*)(ws + off);    off += (size_t)NR*CAP*8;
    bf16_t*  bF        = (bf16_t*)(ws + off);  off += (size_t)384*144*2;
    float*   Wa0       = (float*)(ws + off);   off += 128*16*4;
    float*   bcomb     = (float*)(ws + off);   off += 256;
    bf16_t*  b2        = (bf16_t*)(ws + off);  off += (size_t)128*144*2;

    const int GB = ((N_NODES + 15)/16 + 3)/4;   // 782 gemm blocks (full)
    const int FB = FCAP/64;                      // 128 indirect gemm blocks (worst case)

    // ---- CSR build (LDS counting sort) ----
    zero_cnt_kernel    <<<1, NR, 0, stream>>>(bucket_cnt);
    block_sort_kernel  <<<NSB, 256, 0, stream>>>(ei, bucket_cnt, pairs2);
    rbase_scan_kernel  <<<1, NR, 0, stream>>>(bucket_cnt, rbase);
    csr_finalize_kernel<<<NR, 512, 0, stream>>>(pairs2, bucket_cnt, rbase, col_src, row_ptr);
    build_frontier_kernel<<<1, 256, 0, stream>>>(tgt, row_ptr, col_src, frontier, fcnt);

    // ---- layer 0, fused GEMM over ALL nodes ----
    const float* Wg0 = gatW;
    wa_kernel<<<1, 128, 0, stream>>>(Wg0, attS, attD, Wa0);
    fused_pack_kernel<INPUT, 384, 144><<<(384*144 + 255)/256, 256, 0, stream>>>(
        lin1W, Wg0, Wa0, lin1b, bF, bcomb);
    mfma_gemm6_kernel<INPUT, 384, 9, 16, 5, false, true, true, true, false><<<GB, 256, 0, stream>>>(
        word, bF, bcomb, H8, a_s, a_d, N_NODES, nullptr, nullptr);
    // layer-0 aggregate: ONLY frontier nodes (sources of targets + targets)
    gat_aggregate_kernel<<<FCAP/4, 256, 0, stream>>>(
        row_ptr, col_src, H8, a_s, a_d, gatB, Xb, frontier, 0, fcnt);

    // ---- layer 1: GEMM over frontier rows only; aggregate only targets ----
    {
        const float* W = gatW + (size_t)HIDDEN*HIDDEN;
        pack_b_kernel<HIDDEN, 128, 144, true><<<(128*144 + 255)/256, 256, 0, stream>>>(
            W, attS + HEADS*HEAD_DIM, attD + HEADS*HEAD_DIM, b2);
        mfma_gemm6_kernel<HIDDEN, 128, 9, 16, 4, true, false, true, true, true><<<FB, 256, 0, stream>>>(
            Xb, b2, nullptr, H8, a_s, a_d, N_NODES, frontier, fcnt);
        gat_aggregate_kernel<<<(BATCH + 3)/4, 256, 0, stream>>>(
            row_ptr, col_src, H8, a_s, a_d, gatB + HIDDEN, Xb, tgt, BATCH, nullptr);
    }

    head_kernel<<<1, 64, 0, stream>>>(Xb, tgt, lin3W, lin3b, (float*)d_out);
}